// Round 4
// baseline (958.791 us; speedup 1.0000x reference)
//
#include <hip/hip_runtime.h>
#include <hip/hip_bf16.h>
#include <math.h>

#define HDIM 128
#define INVD 16
#define DIN 272           // 2*H + INV
#define TE 64             // edges per tile
#define NB 64             // nodes per batch (CSR kernel)
#define NKT 9             // K steps of 32 -> 288 (pad 272->288)
#define LDA 296           // A row stride in bf16 elems (592 B)
#define LDN 132           // Nacc row stride in floats (bank-spread)

typedef __attribute__((ext_vector_type(4))) float f32x4;
typedef __attribute__((ext_vector_type(4))) float float4v;
typedef __attribute__((ext_vector_type(8))) short bf16x8;
typedef __attribute__((ext_vector_type(4))) short bf16x4;

__device__ inline short f2bf(float f) {
    union { float f; unsigned u; } v; v.f = f;
    unsigned r = v.u + 0x7FFFu + ((v.u >> 16) & 1u);   // RNE
    return (short)(r >> 16);
}

// ---------------- CSR build ----------------
__global__ void hist_kernel(const int* __restrict__ index, int* __restrict__ cnt, int E) {
    int e = blockIdx.x * blockDim.x + threadIdx.x;
    if (e < E) atomicAdd(&cnt[index[E + e]], 1);
}

__global__ __launch_bounds__(1024) void scan_kernel(const int* __restrict__ cnt,
                                                    int* __restrict__ off,
                                                    int* __restrict__ cur, int N) {
    __shared__ int psum[1024];
    const int t = threadIdx.x;
    const int C = (N + 1023) >> 10;
    const int a0 = t * C;
    const int a1 = (a0 + C < N) ? a0 + C : N;
    int s = 0;
    for (int i = a0; i < a1; ++i) s += cnt[i];
    psum[t] = s;
    __syncthreads();
    for (int d = 1; d < 1024; d <<= 1) {
        int v = (t >= d) ? psum[t - d] : 0;
        __syncthreads();
        psum[t] += v;
        __syncthreads();
    }
    int run = (t > 0) ? psum[t - 1] : 0;
    for (int i = a0; i < a1; ++i) {
        off[i] = run; cur[i] = run;
        run += cnt[i];
    }
    if (t == 1023) off[N] = psum[1023];
}

__global__ void fill_kernel(const int* __restrict__ index, int* __restrict__ cur,
                            int* __restrict__ eid, int E) {
    int e = blockIdx.x * blockDim.x + threadIdx.x;
    if (e < E) { int p = atomicAdd(&cur[index[E + e]], 1); eid[p] = e; }
}

// ---------------- main CSR kernel ----------------
__global__ __launch_bounds__(256) void etnn_csr_kernel(
    const float* __restrict__ x_send,
    const float* __restrict__ x_rec,
    const int*   __restrict__ index,     // [2][E] int32
    const float* __restrict__ edge_attr, // [E][16]
    const float* __restrict__ bn_gamma,
    const float* __restrict__ bn_beta,
    const float* __restrict__ bn_mean,
    const float* __restrict__ bn_var,
    const float* __restrict__ W1,        // [DIN][H]
    const float* __restrict__ b1,
    const float* __restrict__ W2,
    const float* __restrict__ b2,
    const int*   __restrict__ off,       // [N+1]
    const int*   __restrict__ eid,       // [E]
    float* __restrict__ out,             // [N][H]
    int E, int N)
{
    __shared__ short Atile[TE * LDA];              // 37888 B
    __shared__ float Nacc[NB * LDN];               // 33792 B
    __shared__ float scl[DIN];
    __shared__ float shf[DIN];
    __shared__ __align__(16) float pdot[TE][4];
    __shared__ int   lrow[TE];

    const int tid = threadIdx.x;
    const int w  = tid >> 6;
    const int l  = tid & 63;
    const int lr = l & 15;
    const int lg = l >> 4;

    for (int c = tid; c < DIN; c += 256) {
        float sc = bn_gamma[c] * rsqrtf(bn_var[c] + 1e-5f);
        scl[c] = sc;
        shf[c] = bn_beta[c] - bn_mean[c] * sc;
    }
    __syncthreads();

    // W1 -> bf16 B fragments (BN scale folded); BN shift folded into bias
    bf16x8 Bf[NKT][2];
    float biasv[2], w2v[2];
    #pragma unroll
    for (int nt = 0; nt < 2; ++nt) {
        const int col = w * 32 + nt * 16 + lr;
        float bsum = 0.f;
        #pragma unroll
        for (int kk = 0; kk < NKT; ++kk) {
            bf16x8 bv;
            const int kbase = kk * 32 + lg * 8;
            #pragma unroll
            for (int j = 0; j < 8; ++j) {
                const int k = kbase + j;
                float v = 0.f;
                if (k < DIN) {
                    float wv = W1[k * HDIM + col];
                    v = scl[k] * wv;
                    bsum += shf[k] * wv;
                }
                bv[j] = f2bf(v);
            }
            Bf[kk][nt] = bv;
        }
        bsum += __shfl_xor(bsum, 16, 64);
        bsum += __shfl_xor(bsum, 32, 64);
        biasv[nt] = b1[col] + bsum;
        w2v[nt]   = W2[col];
    }
    const float b2v = b2[0];

    const int nb = (N + NB - 1) / NB;
    for (int b = blockIdx.x; b < nb; b += gridDim.x) {
        const int n0 = b * NB;
        const int n1 = (n0 + NB < N) ? n0 + NB : N;

        // zero the node accumulator
        for (int i = tid; i < (NB * LDN) / 4; i += 256)
            ((f32x4*)Nacc)[i] = (f32x4){0.f, 0.f, 0.f, 0.f};
        __syncthreads();

        const int p0 = off[n0];
        const int p1 = off[n1];

        for (int p = p0; p < p1; p += TE) {
            // -------- stage: gather + cvt -> LDS A tile --------
            {
                const int r = tid >> 2;
                const int q = tid & 3;
                const int pos = p + r;
                short* arow = &Atile[r * LDA];
                if (pos < p1) {
                    const int e  = eid[pos];
                    const int is = index[e];
                    const int ir = index[E + e];
                    if (q == 0) lrow[r] = ir - n0;
                    const float4v* ps = (const float4v*)(x_send + (size_t)is * HDIM);
                    const float4v* pr = (const float4v*)(x_rec  + (size_t)ir * HDIM);
                    #pragma unroll
                    for (int i = 0; i < 8; ++i) {
                        float4v v = ps[q + i * 4];
                        bf16x4 o; o[0]=f2bf(v[0]); o[1]=f2bf(v[1]); o[2]=f2bf(v[2]); o[3]=f2bf(v[3]);
                        *(bf16x4*)(arow + (q + i * 4) * 4) = o;
                    }
                    #pragma unroll
                    for (int i = 0; i < 8; ++i) {
                        float4v v = pr[q + i * 4];
                        bf16x4 o; o[0]=f2bf(v[0]); o[1]=f2bf(v[1]); o[2]=f2bf(v[2]); o[3]=f2bf(v[3]);
                        *(bf16x4*)(arow + 128 + (q + i * 4) * 4) = o;
                    }
                    {
                        float4v v = *(const float4v*)(edge_attr + (size_t)e * INVD + q * 4);
                        bf16x4 o; o[0]=f2bf(v[0]); o[1]=f2bf(v[1]); o[2]=f2bf(v[2]); o[3]=f2bf(v[3]);
                        *(bf16x4*)(arow + 256 + q * 4) = o;
                    }
                    bf16x4 z = {0, 0, 0, 0};
                    *(bf16x4*)(arow + 272 + q * 4) = z;
                } else {
                    if (q == 0) lrow[r] = -1;
                    bf16x4 z = {0, 0, 0, 0};
                    #pragma unroll
                    for (int i = 0; i < 18; ++i)
                        *(bf16x4*)(arow + q * 4 + i * 16) = z;
                }
            }
            __syncthreads();

            // -------- MFMA --------
            f32x4 acc[4][2];
            #pragma unroll
            for (int mt = 0; mt < 4; ++mt) {
                acc[mt][0] = (f32x4){0.f, 0.f, 0.f, 0.f};
                acc[mt][1] = (f32x4){0.f, 0.f, 0.f, 0.f};
            }
            #pragma unroll
            for (int kk = 0; kk < NKT; ++kk) {
                #pragma unroll
                for (int mt = 0; mt < 4; ++mt) {
                    bf16x8 a = *(const bf16x8*)(&Atile[(mt * 16 + lr) * LDA + kk * 32 + lg * 8]);
                    acc[mt][0] = __builtin_amdgcn_mfma_f32_16x16x32_bf16(a, Bf[kk][0], acc[mt][0], 0, 0, 0);
                    acc[mt][1] = __builtin_amdgcn_mfma_f32_16x16x32_bf16(a, Bf[kk][1], acc[mt][1], 0, 0, 0);
                }
            }

            // -------- SiLU + per-wave partial gate dot --------
            #pragma unroll
            for (int mt = 0; mt < 4; ++mt) {
                #pragma unroll
                for (int r = 0; r < 4; ++r) {
                    float pdv = 0.f;
                    #pragma unroll
                    for (int nt = 0; nt < 2; ++nt) {
                        float z = acc[mt][nt][r] + biasv[nt];
                        float m = z / (1.f + __expf(-z));   // SiLU
                        acc[mt][nt][r] = m;
                        pdv += m * w2v[nt];
                    }
                    pdv += __shfl_xor(pdv, 1, 64);
                    pdv += __shfl_xor(pdv, 2, 64);
                    pdv += __shfl_xor(pdv, 4, 64);
                    pdv += __shfl_xor(pdv, 8, 64);
                    if (lr == 0) pdot[mt * 16 + lg * 4 + r][w] = pdv;
                }
            }
            __syncthreads();

            // -------- gate + LDS accumulate (ds atomics, no global atomics) --------
            #pragma unroll
            for (int mt = 0; mt < 4; ++mt) {
                #pragma unroll
                for (int r = 0; r < 4; ++r) {
                    const int rr = mt * 16 + lg * 4 + r;
                    const int ln = lrow[rr];
                    if (ln >= 0) {
                        f32x4 pv = *(const f32x4*)pdot[rr];
                        float s = pv[0] + pv[1] + pv[2] + pv[3] + b2v;
                        float g = 1.f / (1.f + __expf(-s));
                        float* nrow = &Nacc[ln * LDN + w * 32 + lr];
                        atomicAdd(nrow,      acc[mt][0][r] * g);
                        atomicAdd(nrow + 16, acc[mt][1][r] * g);
                    }
                }
            }
            __syncthreads();   // before next tile overwrites Atile/lrow/pdot
        }

        // -------- batch write-out (coalesced, no atomics): all 128 cols --------
        {
            const int j = tid >> 2;       // node row 0..63
            const int q = tid & 3;        // quarter
            if (n0 + j < n1) {
                f32x4* orow = (f32x4*)(out + (size_t)(n0 + j) * HDIM);
                #pragma unroll
                for (int i = 0; i < 8; ++i) {
                    const int c4 = q + i * 4;         // 0..31 -> float cols c4*4..c4*4+3
                    orow[c4] = *(const f32x4*)&Nacc[j * LDN + c4 * 4];
                }
            }
        }
        __syncthreads();   // before next batch zeroes Nacc
    }
}

extern "C" void kernel_launch(void* const* d_in, const int* in_sizes, int n_in,
                              void* d_out, int out_size, void* d_ws, size_t ws_size,
                              hipStream_t stream) {
    const float* x_send    = (const float*)d_in[0];
    const float* x_rec     = (const float*)d_in[1];
    const int*   index     = (const int*)d_in[2];
    const float* edge_attr = (const float*)d_in[3];
    const float* bn_gamma  = (const float*)d_in[4];
    const float* bn_beta   = (const float*)d_in[5];
    const float* bn_mean   = (const float*)d_in[6];
    const float* bn_var    = (const float*)d_in[7];
    const float* W1        = (const float*)d_in[8];
    const float* b1        = (const float*)d_in[9];
    const float* W2        = (const float*)d_in[10];
    const float* b2        = (const float*)d_in[11];
    float* out = (float*)d_out;

    const int E = in_sizes[3] / INVD;
    const int N = in_sizes[0] / HDIM;

    int* cnt = (int*)d_ws;
    int* off = cnt + N;
    int* cur = off + N + 1;
    int* eid = cur + N;
    hipMemsetAsync(cnt, 0, (size_t)N * sizeof(int), stream);
    hist_kernel<<<(E + 255) / 256, 256, 0, stream>>>(index, cnt, E);
    scan_kernel<<<1, 1024, 0, stream>>>(cnt, off, cur, N);
    fill_kernel<<<(E + 255) / 256, 256, 0, stream>>>(index, cur, eid, E);
    const int nb = (N + NB - 1) / NB;
    const int grid = nb < 512 ? nb : 512;
    etnn_csr_kernel<<<grid, 256, 0, stream>>>(x_send, x_rec, index, edge_attr,
                                              bn_gamma, bn_beta, bn_mean, bn_var,
                                              W1, b1, W2, b2, off, eid, out, E, N);
}

// Round 5
// 409.139 us; speedup vs baseline: 2.3434x; 2.3434x over previous
//
#include <hip/hip_runtime.h>
#include <hip/hip_bf16.h>
#include <math.h>

#define HDIM 128
#define INVD 16
#define DIN 272           // 2*H + INV
#define NKT 9             // K steps of 32 -> 288 (pad 272->288)

typedef __attribute__((ext_vector_type(4))) float f32x4;
typedef __attribute__((ext_vector_type(8))) short bf16x8;

__device__ inline short f2bf(float f) {
    union { float f; unsigned u; } v; v.f = f;
    unsigned r = v.u + 0x7FFFu + ((v.u >> 16) & 1u);   // RNE
    return (short)(r >> 16);
}

// Barrier-free main loop: each wave owns 16 edges x 128 cols.
// W1 (BN-scale folded, bf16) pre-packed in LDS as MFMA B-fragments, read-only.
__global__ __launch_bounds__(256, 2) void etnn_kernel(
    const float* __restrict__ x_send,
    const float* __restrict__ x_rec,
    const int*   __restrict__ index,     // [2][E] int32
    const float* __restrict__ edge_attr, // [E][16]
    const float* __restrict__ bn_gamma,
    const float* __restrict__ bn_beta,
    const float* __restrict__ bn_mean,
    const float* __restrict__ bn_var,
    const float* __restrict__ W1,        // [DIN][H]
    const float* __restrict__ b1,
    const float* __restrict__ W2,
    const float* __restrict__ b2,
    float* __restrict__ out,             // [N][H]
    int E, int nIter)
{
    // [kk][cb][lane][8 bf16] : 9*8*64*8 shorts = 73728 B
    __shared__ short btab[NKT * 8 * 64 * 8];
    __shared__ float scl[DIN];
    __shared__ float shf[DIN];
    __shared__ float bias2[2][HDIM];
    __shared__ float biasT[HDIM];

    const int tid = threadIdx.x;
    const int l  = tid & 63;
    const int lr = l & 15;     // row within 16 (A) / col within 16 (C)
    const int lg = l >> 4;     // k-group 0..3 / row-group (C)

    // ---- BN constants ----
    for (int c = tid; c < DIN; c += 256) {
        float sc = bn_gamma[c] * rsqrtf(bn_var[c] + 1e-5f);
        scl[c] = sc;
        shf[c] = bn_beta[c] - bn_mean[c] * sc;
    }
    __syncthreads();

    // ---- build B-fragment table (BN scale folded into W) ----
    for (int f = tid; f < NKT * 8 * 64; f += 256) {
        const int kk  = f >> 9;          // /(8*64)
        const int cb  = (f >> 6) & 7;
        const int ln  = f & 63;
        const int k0  = kk * 32 + (ln >> 4) * 8;
        const int col = cb * 16 + (ln & 15);
        bf16x8 bv;
        #pragma unroll
        for (int j = 0; j < 8; ++j) {
            const int k = k0 + j;
            float v = (k < DIN) ? scl[k] * W1[k * HDIM + col] : 0.f;
            bv[j] = f2bf(v);
        }
        *(bf16x8*)&btab[f * 8] = bv;
    }
    // ---- bias fold: biasT[col] = b1[col] + sum_k shf[k]*W1[k][col] ----
    {
        const int col  = tid & 127;
        const int half = tid >> 7;
        float s = 0.f;
        for (int k = half * 136; k < half * 136 + 136; ++k)
            s += shf[k] * W1[k * HDIM + col];
        bias2[half][col] = s;
    }
    __syncthreads();
    if (tid < HDIM) biasT[tid] = b1[tid] + bias2[0][tid] + bias2[1][tid];
    __syncthreads();
    // ---- after this point: NO barriers; btab/biasT are read-only ----

    float biasv[8], w2v[8];
    #pragma unroll
    for (int cb = 0; cb < 8; ++cb) {
        biasv[cb] = biasT[cb * 16 + lr];
        w2v[cb]   = W2[cb * 16 + lr];
    }
    const float b2v = b2[0];

    const int gw = blockIdx.x * 4 + (tid >> 6);
    const int NW = gridDim.x * 4;

    for (int it = gw; it < nIter; it += NW) {
        const int e0 = it * 16;
        const int e  = e0 + lr;
        const int ec = (e < E) ? e : E - 1;
        const int is = index[ec];
        const int ir = index[E + ec];

        // -------- gather: 18 independent f32x4 loads, all issued up front ----
        const f32x4* ps = (const f32x4*)(x_send + (size_t)is * HDIM);
        const f32x4* pr = (const f32x4*)(x_rec  + (size_t)ir * HDIM);
        f32x4 Ls[8], Lr[8], La[2];
        #pragma unroll
        for (int kk = 0; kk < 4; ++kk) {
            Ls[kk * 2]     = ps[kk * 8 + lg * 2];
            Ls[kk * 2 + 1] = ps[kk * 8 + lg * 2 + 1];
            Lr[kk * 2]     = pr[kk * 8 + lg * 2];
            Lr[kk * 2 + 1] = pr[kk * 8 + lg * 2 + 1];
        }
        if (lg < 2) {
            const f32x4* pa = (const f32x4*)(edge_attr + (size_t)ec * INVD + lg * 8);
            La[0] = pa[0]; La[1] = pa[1];
        } else {
            La[0] = (f32x4){0.f, 0.f, 0.f, 0.f};
            La[1] = (f32x4){0.f, 0.f, 0.f, 0.f};
        }

        // -------- MFMA: 9 k-steps x 8 col-blocks --------
        f32x4 acc[8];
        #pragma unroll
        for (int cb = 0; cb < 8; ++cb) acc[cb] = (f32x4){0.f, 0.f, 0.f, 0.f};

        #pragma unroll
        for (int kk = 0; kk < NKT; ++kk) {
            f32x4 lo = (kk < 4) ? Ls[kk * 2]     : (kk < 8) ? Lr[(kk - 4) * 2]     : La[0];
            f32x4 hi = (kk < 4) ? Ls[kk * 2 + 1] : (kk < 8) ? Lr[(kk - 4) * 2 + 1] : La[1];
            bf16x8 a;
            a[0] = f2bf(lo[0]); a[1] = f2bf(lo[1]); a[2] = f2bf(lo[2]); a[3] = f2bf(lo[3]);
            a[4] = f2bf(hi[0]); a[5] = f2bf(hi[1]); a[6] = f2bf(hi[2]); a[7] = f2bf(hi[3]);
            #pragma unroll
            for (int cb = 0; cb < 8; ++cb) {
                bf16x8 b = *(const bf16x8*)&btab[((kk * 8 + cb) * 64 + l) * 8];
                acc[cb] = __builtin_amdgcn_mfma_f32_16x16x32_bf16(a, b, acc[cb], 0, 0, 0);
            }
        }

        // -------- SiLU + gate dot (16-lane reduce) --------
        float p[4] = {0.f, 0.f, 0.f, 0.f};
        #pragma unroll
        for (int cb = 0; cb < 8; ++cb) {
            #pragma unroll
            for (int q = 0; q < 4; ++q) {
                float z = acc[cb][q] + biasv[cb];
                float m = z / (1.f + __expf(-z));   // SiLU
                acc[cb][q] = m;
                p[q] += m * w2v[cb];
            }
        }
        #pragma unroll
        for (int q = 0; q < 4; ++q) {
            p[q] += __shfl_xor(p[q], 1, 64);
            p[q] += __shfl_xor(p[q], 2, 64);
            p[q] += __shfl_xor(p[q], 4, 64);
            p[q] += __shfl_xor(p[q], 8, 64);
        }

        // -------- gated scatter (fire-and-forget atomics) --------
        #pragma unroll
        for (int q = 0; q < 4; ++q) {
            const int row = lg * 4 + q;          // C row within the 16-edge tile
            if (e0 + row < E) {
                const int irq = __shfl(ir, (l & 48) | row, 64);
                const float g = 1.f / (1.f + __expf(-(p[q] + b2v)));
                float* orow = out + (size_t)irq * HDIM + lr;
                #pragma unroll
                for (int cb = 0; cb < 8; ++cb)
                    atomicAdd(orow + cb * 16, acc[cb][q] * g);
            }
        }
    }
}

extern "C" void kernel_launch(void* const* d_in, const int* in_sizes, int n_in,
                              void* d_out, int out_size, void* d_ws, size_t ws_size,
                              hipStream_t stream) {
    const float* x_send    = (const float*)d_in[0];
    const float* x_rec     = (const float*)d_in[1];
    const int*   index     = (const int*)d_in[2];
    const float* edge_attr = (const float*)d_in[3];
    const float* bn_gamma  = (const float*)d_in[4];
    const float* bn_beta   = (const float*)d_in[5];
    const float* bn_mean   = (const float*)d_in[6];
    const float* bn_var    = (const float*)d_in[7];
    const float* W1        = (const float*)d_in[8];
    const float* b1        = (const float*)d_in[9];
    const float* W2        = (const float*)d_in[10];
    const float* b2        = (const float*)d_in[11];
    float* out = (float*)d_out;

    const int E = in_sizes[3] / INVD;
    const int nIter = (E + 15) / 16;

    hipMemsetAsync(d_out, 0, (size_t)out_size * sizeof(float), stream);

    const int grid = 512;   // 2 blocks/CU (LDS-limited), 8 free-running waves/CU
    etnn_kernel<<<grid, 256, 0, stream>>>(x_send, x_rec, index, edge_attr,
                                          bn_gamma, bn_beta, bn_mean, bn_var,
                                          W1, b1, W2, b2, out, E, nIter);
}

// Round 6
// 322.623 us; speedup vs baseline: 2.9719x; 1.2682x over previous
//
#include <hip/hip_runtime.h>
#include <hip/hip_bf16.h>
#include <hip/hip_fp16.h>
#include <math.h>

#define HDIM 128
#define INVD 16
#define DIN 272           // 2*H + INV
#define TE 64             // edges per tile
#define NKT 9             // K steps of 32 -> 288 (pad 272->288)
#define LDA 296           // A row stride in bf16 elems (592 B)
#define LDH 136           // f16 message-tile row stride (272 B, bank-spread)

typedef __attribute__((ext_vector_type(4))) float f32x4;
typedef __attribute__((ext_vector_type(4))) float float4v;
typedef __attribute__((ext_vector_type(8))) short bf16x8;
typedef __attribute__((ext_vector_type(4))) short bf16x4;

__device__ inline short f2bf(float f) {
    union { float f; unsigned u; } v; v.f = f;
    unsigned r = v.u + 0x7FFFu + ((v.u >> 16) & 1u);   // RNE
    return (short)(r >> 16);
}

template<bool WS>
__global__ __launch_bounds__(256) void etnn_kernel(
    const float* __restrict__ x_send,
    const float* __restrict__ x_rec,
    const int*   __restrict__ index,     // [2][E] int32
    const float* __restrict__ edge_attr, // [E][16]
    const float* __restrict__ bn_gamma,
    const float* __restrict__ bn_beta,
    const float* __restrict__ bn_mean,
    const float* __restrict__ bn_var,
    const float* __restrict__ W1,        // [DIN][H]
    const float* __restrict__ b1,
    const float* __restrict__ W2,
    const float* __restrict__ b2,
    float* __restrict__ out,             // [N][H] (fallback path)
    __half* __restrict__ ws,             // [N][H] f16 accumulator (WS path)
    int E)
{
    __shared__ short Atile[TE * LDA];     // 37888 B; reused as f16 msg[64][136]
    __shared__ float scl[DIN];
    __shared__ float shf[DIN];
    __shared__ __align__(16) float pdot[TE][4];
    __shared__ int   ridx[TE];

    const int tid = threadIdx.x;
    const int w  = tid >> 6;   // wave id 0..3 -> cols [w*32, w*32+32)
    const int l  = tid & 63;
    const int lr = l & 15;
    const int lg = l >> 4;

    for (int c = tid; c < DIN; c += 256) {
        float sc = bn_gamma[c] * rsqrtf(bn_var[c] + 1e-5f);
        scl[c] = sc;
        shf[c] = bn_beta[c] - bn_mean[c] * sc;
    }
    __syncthreads();

    // W1 -> bf16 B fragments (BN scale folded); BN shift folded into bias
    bf16x8 Bf[NKT][2];
    float biasv[2], w2v[2];
    #pragma unroll
    for (int nt = 0; nt < 2; ++nt) {
        const int col = w * 32 + nt * 16 + lr;
        float bsum = 0.f;
        #pragma unroll
        for (int kk = 0; kk < NKT; ++kk) {
            bf16x8 bv;
            const int kbase = kk * 32 + lg * 8;
            #pragma unroll
            for (int j = 0; j < 8; ++j) {
                const int k = kbase + j;
                float v = 0.f;
                if (k < DIN) {
                    float wv = W1[k * HDIM + col];
                    v = scl[k] * wv;
                    bsum += shf[k] * wv;
                }
                bv[j] = f2bf(v);
            }
            Bf[kk][nt] = bv;
        }
        bsum += __shfl_xor(bsum, 16, 64);
        bsum += __shfl_xor(bsum, 32, 64);
        biasv[nt] = b1[col] + bsum;
        w2v[nt]   = W2[col];
    }
    const float b2v = b2[0];

    const int numTiles = (E + TE - 1) / TE;
    for (int t = blockIdx.x; t < numTiles; t += gridDim.x) {
        __syncthreads();   // protect Atile/ridx/pdot from prev-tile readers
        const int e0 = t * TE;

        // -------- Phase 1: gather + cvt -> LDS A tile --------
        {
            const int r = tid >> 2;
            const int q = tid & 3;
            const int e = e0 + r;
            short* arow = &Atile[r * LDA];
            if (e < E) {
                const int is = index[e];
                const int ir = index[E + e];
                if (q == 0) ridx[r] = ir;
                const float4v* ps = (const float4v*)(x_send + (size_t)is * HDIM);
                const float4v* pr = (const float4v*)(x_rec  + (size_t)ir * HDIM);
                #pragma unroll
                for (int i = 0; i < 8; ++i) {
                    float4v v = ps[q + i * 4];
                    bf16x4 o; o[0]=f2bf(v[0]); o[1]=f2bf(v[1]); o[2]=f2bf(v[2]); o[3]=f2bf(v[3]);
                    *(bf16x4*)(arow + (q + i * 4) * 4) = o;
                }
                #pragma unroll
                for (int i = 0; i < 8; ++i) {
                    float4v v = pr[q + i * 4];
                    bf16x4 o; o[0]=f2bf(v[0]); o[1]=f2bf(v[1]); o[2]=f2bf(v[2]); o[3]=f2bf(v[3]);
                    *(bf16x4*)(arow + 128 + (q + i * 4) * 4) = o;
                }
                {
                    float4v v = *(const float4v*)(edge_attr + (size_t)e * INVD + q * 4);
                    bf16x4 o; o[0]=f2bf(v[0]); o[1]=f2bf(v[1]); o[2]=f2bf(v[2]); o[3]=f2bf(v[3]);
                    *(bf16x4*)(arow + 256 + q * 4) = o;
                }
                bf16x4 z = {0, 0, 0, 0};
                *(bf16x4*)(arow + 272 + q * 4) = z;
            } else {
                if (q == 0) ridx[r] = -1;
                bf16x4 z = {0, 0, 0, 0};
                #pragma unroll
                for (int i = 0; i < 18; ++i)
                    *(bf16x4*)(arow + q * 4 + i * 16) = z;
            }
        }
        __syncthreads();

        // -------- Phase 2: MFMA --------
        f32x4 acc[4][2];
        #pragma unroll
        for (int mt = 0; mt < 4; ++mt) {
            acc[mt][0] = (f32x4){0.f, 0.f, 0.f, 0.f};
            acc[mt][1] = (f32x4){0.f, 0.f, 0.f, 0.f};
        }
        #pragma unroll
        for (int kk = 0; kk < NKT; ++kk) {
            #pragma unroll
            for (int mt = 0; mt < 4; ++mt) {
                bf16x8 a = *(const bf16x8*)(&Atile[(mt * 16 + lr) * LDA + kk * 32 + lg * 8]);
                acc[mt][0] = __builtin_amdgcn_mfma_f32_16x16x32_bf16(a, Bf[kk][0], acc[mt][0], 0, 0, 0);
                acc[mt][1] = __builtin_amdgcn_mfma_f32_16x16x32_bf16(a, Bf[kk][1], acc[mt][1], 0, 0, 0);
            }
        }

        // -------- Phase 3a: SiLU + per-wave partial gate dot --------
        #pragma unroll
        for (int mt = 0; mt < 4; ++mt) {
            #pragma unroll
            for (int r = 0; r < 4; ++r) {
                float pdv = 0.f;
                #pragma unroll
                for (int nt = 0; nt < 2; ++nt) {
                    float z = acc[mt][nt][r] + biasv[nt];
                    float m = z / (1.f + __expf(-z));   // SiLU
                    acc[mt][nt][r] = m;
                    pdv += m * w2v[nt];
                }
                pdv += __shfl_xor(pdv, 1, 64);
                pdv += __shfl_xor(pdv, 2, 64);
                pdv += __shfl_xor(pdv, 4, 64);
                pdv += __shfl_xor(pdv, 8, 64);
                if (lr == 0) pdot[mt * 16 + lg * 4 + r][w] = pdv;
            }
        }
        __syncthreads();   // pdot ready; all waves done reading Atile

        if constexpr (WS) {
            // ---- Phase 3b: gate + f16 transpose into msg tile (overlays Atile)
            __half* Lh = (__half*)Atile;
            #pragma unroll
            for (int mt = 0; mt < 4; ++mt) {
                #pragma unroll
                for (int r = 0; r < 4; ++r) {
                    const int rr = mt * 16 + lg * 4 + r;
                    f32x4 pv = *(const f32x4*)pdot[rr];
                    float s = pv[0] + pv[1] + pv[2] + pv[3] + b2v;
                    float g = 1.f / (1.f + __expf(-s));
                    Lh[rr * LDH + w * 32 + lr]      = __float2half(acc[mt][0][r] * g);
                    Lh[rr * LDH + w * 32 + 16 + lr] = __float2half(acc[mt][1][r] * g);
                }
            }
            __syncthreads();

            // ---- Phase 4: packed-f16 atomic scatter, 256 B contiguous/instr
            #pragma unroll
            for (int i = 0; i < 16; ++i) {
                const int row = w * 16 + i;
                const int node = ridx[row];
                if (node >= 0) {
                    unsigned d = *(const unsigned*)&Lh[row * LDH + 2 * l];
                    unsigned long long a =
                        (unsigned long long)(ws + (size_t)node * HDIM + 2 * l);
                    asm volatile("global_atomic_pk_add_f16 %0, %1, off"
                                 :: "v"(a), "v"(d) : "memory");
                }
            }
        } else {
            // ---- fallback: per-lane gate + scalar f32 atomics (R1 path) ----
            #pragma unroll
            for (int mt = 0; mt < 4; ++mt) {
                #pragma unroll
                for (int r = 0; r < 4; ++r) {
                    const int rr = mt * 16 + lg * 4 + r;
                    const int node = ridx[rr];
                    if (node >= 0) {
                        f32x4 pv = *(const f32x4*)pdot[rr];
                        float s = pv[0] + pv[1] + pv[2] + pv[3] + b2v;
                        float g = 1.f / (1.f + __expf(-s));
                        float* orow = out + (size_t)node * HDIM + w * 32 + lr;
                        atomicAdd(orow,      acc[mt][0][r] * g);
                        atomicAdd(orow + 16, acc[mt][1][r] * g);
                    }
                }
            }
        }
    }
}

__global__ __launch_bounds__(256) void cvt_kernel(const __half* __restrict__ ws,
                                                  float* __restrict__ out, int n) {
    int i = (blockIdx.x * 256 + threadIdx.x) * 4;
    if (i < n) {
        const __half2* p = (const __half2*)(ws + i);
        float2 a = __half22float2(p[0]);
        float2 b = __half22float2(p[1]);
        f32x4 v = {a.x, a.y, b.x, b.y};
        *(f32x4*)(out + i) = v;
    }
}

extern "C" void kernel_launch(void* const* d_in, const int* in_sizes, int n_in,
                              void* d_out, int out_size, void* d_ws, size_t ws_size,
                              hipStream_t stream) {
    const float* x_send    = (const float*)d_in[0];
    const float* x_rec     = (const float*)d_in[1];
    const int*   index     = (const int*)d_in[2];
    const float* edge_attr = (const float*)d_in[3];
    const float* bn_gamma  = (const float*)d_in[4];
    const float* bn_beta   = (const float*)d_in[5];
    const float* bn_mean   = (const float*)d_in[6];
    const float* bn_var    = (const float*)d_in[7];
    const float* W1        = (const float*)d_in[8];
    const float* b1        = (const float*)d_in[9];
    const float* W2        = (const float*)d_in[10];
    const float* b2        = (const float*)d_in[11];
    float* out = (float*)d_out;

    const int E = in_sizes[3] / INVD;
    const int N = in_sizes[0] / HDIM;
    const int numTiles = (E + TE - 1) / TE;
    const int grid = numTiles < 768 ? numTiles : 768;

    const size_t need = (size_t)N * HDIM * sizeof(__half);
    if (ws_size >= need) {
        __half* ws = (__half*)d_ws;
        hipMemsetAsync(ws, 0, need, stream);
        etnn_kernel<true><<<grid, 256, 0, stream>>>(x_send, x_rec, index, edge_attr,
                                                    bn_gamma, bn_beta, bn_mean, bn_var,
                                                    W1, b1, W2, b2, out, ws, E);
        const int n = N * HDIM;
        cvt_kernel<<<(n / 4 + 255) / 256, 256, 0, stream>>>(ws, out, n);
    } else {
        hipMemsetAsync(d_out, 0, (size_t)out_size * sizeof(float), stream);
        etnn_kernel<false><<<grid, 256, 0, stream>>>(x_send, x_rec, index, edge_attr,
                                                     bn_gamma, bn_beta, bn_mean, bn_var,
                                                     W1, b1, W2, b2, out, nullptr, E);
    }
}

// Round 8
// 193.698 us; speedup vs baseline: 4.9499x; 1.6656x over previous
//
#include <hip/hip_runtime.h>
#include <hip/hip_bf16.h>
#include <hip/hip_fp16.h>
#include <math.h>

#define HDIM 128
#define INVD 16
#define DIN 272           // 2*H + INV
#define NKT 9             // K steps of 32 -> 288 (pad 272->288)

typedef __attribute__((ext_vector_type(4))) float f32x4;
typedef __attribute__((ext_vector_type(8))) short bf16x8;
typedef __attribute__((ext_vector_type(2))) __fp16 fp16x2;

__device__ inline short f2bf(float f) {
    union { float f; unsigned u; } v; v.f = f;
    unsigned r = v.u + 0x7FFFu + ((v.u >> 16) & 1u);   // RNE
    return (short)(r >> 16);
}

// Barrier-free main loop: each wave owns 16 edges x 128 cols.
// W1 (BN-scale folded, bf16) pre-packed in LDS as MFMA B-fragments, read-only.
// Scatter: in-register f16 pair packing -> global_atomic_pk_add_f16, each
// wave-instruction covers 4 node rows x 64 contiguous bytes (4 full lines).
template<bool WS>
__global__ __launch_bounds__(256, 2) void etnn_kernel(
    const float* __restrict__ x_send,
    const float* __restrict__ x_rec,
    const int*   __restrict__ index,     // [2][E] int32
    const float* __restrict__ edge_attr, // [E][16]
    const float* __restrict__ bn_gamma,
    const float* __restrict__ bn_beta,
    const float* __restrict__ bn_mean,
    const float* __restrict__ bn_var,
    const float* __restrict__ W1,        // [DIN][H]
    const float* __restrict__ b1,
    const float* __restrict__ W2,
    const float* __restrict__ b2,
    float* __restrict__ out,             // [N][H] (fallback path)
    __half* __restrict__ ws,             // [N][H] f16 accumulator (WS path)
    int E, int nIter)
{
    // [kk][cb][lane][8 bf16] : 9*8*64*8 shorts = 73728 B
    __shared__ short btab[NKT * 8 * 64 * 8];
    __shared__ float scl[DIN];
    __shared__ float shf[DIN];
    __shared__ float bias2[2][HDIM];
    __shared__ float biasT[HDIM];

    const int tid = threadIdx.x;
    const int l  = tid & 63;
    const int lr = l & 15;     // edge slot within 16 (A rows / C cols)
    const int lg = l >> 4;     // k-group (A) / row-group (C)

    // ---- BN constants ----
    for (int c = tid; c < DIN; c += 256) {
        float sc = bn_gamma[c] * rsqrtf(bn_var[c] + 1e-5f);
        scl[c] = sc;
        shf[c] = bn_beta[c] - bn_mean[c] * sc;
    }
    __syncthreads();

    // ---- build B-fragment table (BN scale folded into W) ----
    for (int f = tid; f < NKT * 8 * 64; f += 256) {
        const int kk  = f >> 9;          // /(8*64)
        const int cb  = (f >> 6) & 7;
        const int ln  = f & 63;
        const int k0  = kk * 32 + (ln >> 4) * 8;
        const int col = cb * 16 + (ln & 15);
        bf16x8 bv;
        #pragma unroll
        for (int j = 0; j < 8; ++j) {
            const int k = k0 + j;
            float v = (k < DIN) ? scl[k] * W1[k * HDIM + col] : 0.f;
            bv[j] = f2bf(v);
        }
        *(bf16x8*)&btab[f * 8] = bv;
    }
    // ---- bias fold: biasT[col] = b1[col] + sum_k shf[k]*W1[k][col] ----
    {
        const int col  = tid & 127;
        const int half = tid >> 7;
        float s = 0.f;
        for (int k = half * 136; k < half * 136 + 136; ++k)
            s += shf[k] * W1[k * HDIM + col];
        bias2[half][col] = s;
    }
    __syncthreads();
    if (tid < HDIM) biasT[tid] = b1[tid] + bias2[0][tid] + bias2[1][tid];
    __syncthreads();
    // ---- after this point: NO barriers; btab/biasT are read-only ----

    float biasv[8], w2v[8];
    #pragma unroll
    for (int cb = 0; cb < 8; ++cb) {
        biasv[cb] = biasT[cb * 16 + lr];
        w2v[cb]   = W2[cb * 16 + lr];
    }
    const float b2v = b2[0];
    const bool evn = !(lr & 1);

    const int gw = blockIdx.x * 4 + (tid >> 6);
    const int NW = gridDim.x * 4;

    for (int it = gw; it < nIter; it += NW) {
        const int e0 = it * 16;
        const int e  = e0 + lr;
        const int ec = (e < E) ? e : E - 1;
        const int is = index[ec];
        const int ir = index[E + ec];

        // -------- gather: 18 independent f32x4 loads, all issued up front ----
        const f32x4* ps = (const f32x4*)(x_send + (size_t)is * HDIM);
        const f32x4* pr = (const f32x4*)(x_rec  + (size_t)ir * HDIM);
        f32x4 Ls[8], Lr[8], La[2];
        #pragma unroll
        for (int kk = 0; kk < 4; ++kk) {
            Ls[kk * 2]     = ps[kk * 8 + lg * 2];
            Ls[kk * 2 + 1] = ps[kk * 8 + lg * 2 + 1];
            Lr[kk * 2]     = pr[kk * 8 + lg * 2];
            Lr[kk * 2 + 1] = pr[kk * 8 + lg * 2 + 1];
        }
        if (lg < 2) {
            const f32x4* pa = (const f32x4*)(edge_attr + (size_t)ec * INVD + lg * 8);
            La[0] = pa[0]; La[1] = pa[1];
        } else {
            La[0] = (f32x4){0.f, 0.f, 0.f, 0.f};
            La[1] = (f32x4){0.f, 0.f, 0.f, 0.f};
        }

        // -------- MFMA: 9 k-steps x 8 col-blocks --------
        f32x4 acc[8];
        #pragma unroll
        for (int cb = 0; cb < 8; ++cb) acc[cb] = (f32x4){0.f, 0.f, 0.f, 0.f};

        #pragma unroll
        for (int kk = 0; kk < NKT; ++kk) {
            f32x4 lo = (kk < 4) ? Ls[kk * 2]     : (kk < 8) ? Lr[(kk - 4) * 2]     : La[0];
            f32x4 hi = (kk < 4) ? Ls[kk * 2 + 1] : (kk < 8) ? Lr[(kk - 4) * 2 + 1] : La[1];
            bf16x8 a;
            a[0] = f2bf(lo[0]); a[1] = f2bf(lo[1]); a[2] = f2bf(lo[2]); a[3] = f2bf(lo[3]);
            a[4] = f2bf(hi[0]); a[5] = f2bf(hi[1]); a[6] = f2bf(hi[2]); a[7] = f2bf(hi[3]);
            #pragma unroll
            for (int cb = 0; cb < 8; ++cb) {
                bf16x8 b = *(const bf16x8*)&btab[((kk * 8 + cb) * 64 + l) * 8];
                acc[cb] = __builtin_amdgcn_mfma_f32_16x16x32_bf16(a, b, acc[cb], 0, 0, 0);
            }
        }

        // -------- SiLU + gate dot (16-lane reduce) --------
        float p[4] = {0.f, 0.f, 0.f, 0.f};
        #pragma unroll
        for (int cb = 0; cb < 8; ++cb) {
            #pragma unroll
            for (int q = 0; q < 4; ++q) {
                float z = acc[cb][q] + biasv[cb];
                float m = z / (1.f + __expf(-z));   // SiLU
                acc[cb][q] = m;
                p[q] += m * w2v[cb];
            }
        }
        #pragma unroll
        for (int q = 0; q < 4; ++q) {
            p[q] += __shfl_xor(p[q], 1, 64);
            p[q] += __shfl_xor(p[q], 2, 64);
            p[q] += __shfl_xor(p[q], 4, 64);
            p[q] += __shfl_xor(p[q], 8, 64);
        }

        // -------- gated scatter --------
        #pragma unroll
        for (int q = 0; q < 4; ++q) {
            const int row = lg * 4 + q;              // C row (edge) for this group
            if (e0 + row < E) {
                const int irq = __shfl(ir, row, 64); // receiver node of that edge
                const float g = 1.f / (1.f + __expf(-(p[q] + b2v)));
                if constexpr (WS) {
                    // pk-f16 atomics: per instr, 4 rows x 64 contiguous bytes
                    float m[8];
                    #pragma unroll
                    for (int cb = 0; cb < 8; ++cb) m[cb] = acc[cb][q] * g;
                    #pragma unroll
                    for (int c = 0; c < 4; ++c) {
                        float x0 = __shfl_xor(m[2 * c],     1, 64);
                        float x1 = __shfl_xor(m[2 * c + 1], 1, 64);
                        float va = evn ? m[2 * c] : x1;
                        float vb = evn ? x0       : m[2 * c + 1];
                        union { fp16x2 h; unsigned u; } pk;
                        pk.h = __builtin_amdgcn_cvt_pkrtz(va, vb);
                        const int col0 = evn ? (32 * c + lr) : (32 * c + 15 + lr);
                        unsigned long long a =
                            (unsigned long long)(ws + (size_t)irq * HDIM + col0);
                        asm volatile("global_atomic_pk_add_f16 %0, %1, off"
                                     :: "v"(a), "v"(pk.u) : "memory");
                    }
                } else {
                    float* orow = out + (size_t)irq * HDIM + lr;
                    #pragma unroll
                    for (int cb = 0; cb < 8; ++cb)
                        atomicAdd(orow + cb * 16, acc[cb][q] * g);
                }
            }
        }
    }
}

__global__ __launch_bounds__(256) void cvt_kernel(const __half* __restrict__ ws,
                                                  float* __restrict__ out, int n) {
    int i = (blockIdx.x * 256 + threadIdx.x) * 4;
    if (i < n) {
        const __half2* p = (const __half2*)(ws + i);
        float2 a = __half22float2(p[0]);
        float2 b = __half22float2(p[1]);
        f32x4 v = {a.x, a.y, b.x, b.y};
        *(f32x4*)(out + i) = v;
    }
}

extern "C" void kernel_launch(void* const* d_in, const int* in_sizes, int n_in,
                              void* d_out, int out_size, void* d_ws, size_t ws_size,
                              hipStream_t stream) {
    const float* x_send    = (const float*)d_in[0];
    const float* x_rec     = (const float*)d_in[1];
    const int*   index     = (const int*)d_in[2];
    const float* edge_attr = (const float*)d_in[3];
    const float* bn_gamma  = (const float*)d_in[4];
    const float* bn_beta   = (const float*)d_in[5];
    const float* bn_mean   = (const float*)d_in[6];
    const float* bn_var    = (const float*)d_in[7];
    const float* W1        = (const float*)d_in[8];
    const float* b1        = (const float*)d_in[9];
    const float* W2        = (const float*)d_in[10];
    const float* b2        = (const float*)d_in[11];
    float* out = (float*)d_out;

    const int E = in_sizes[3] / INVD;
    const int N = in_sizes[0] / HDIM;
    const int nIter = (E + 15) / 16;
    const int grid = 512;   // 2 blocks/CU (LDS-limited), barrier-free waves

    const size_t need = (size_t)N * HDIM * sizeof(__half);
    if (ws_size >= need) {
        __half* ws = (__half*)d_ws;
        hipMemsetAsync(ws, 0, need, stream);
        etnn_kernel<true><<<grid, 256, 0, stream>>>(x_send, x_rec, index, edge_attr,
                                                    bn_gamma, bn_beta, bn_mean, bn_var,
                                                    W1, b1, W2, b2, out, ws, E, nIter);
        const int n = N * HDIM;
        cvt_kernel<<<(n / 4 + 255) / 256, 256, 0, stream>>>(ws, out, n);
    } else {
        hipMemsetAsync(d_out, 0, (size_t)out_size * sizeof(float), stream);
        etnn_kernel<false><<<grid, 256, 0, stream>>>(x_send, x_rec, index, edge_attr,
                                                     bn_gamma, bn_beta, bn_mean, bn_var,
                                                     W1, b1, W2, b2, out, nullptr, E, nIter);
    }
}